// Round 2
// baseline (501.306 us; speedup 1.0000x reference)
//
#include <hip/hip_runtime.h>
#include <math.h>

// ---- problem sizes ----
constexpr int Bz = 32, Vz = 21, Dz = 512, Pz = 64;
constexpr int INz = Dz * Pz;         // 32768
constexpr int OUTz = 720;
constexpr int Ez = 8, Rz = 16, Hz = 256;
constexpr int Mz = Bz * Vz;          // 672
constexpr int Nz = OUTz + Ez * Rz;   // 848  (base 720 cols + 8*16 lora cols)
constexpr int Kz = INz;              // 32768

// ---- GEMM tiling ----
constexpr int BM = 128, BN = 128, BK = 32;
constexpr int SPLIT = 16;            // split-K factor
constexpr int KSL = Kz / SPLIT;      // 2048
constexpr int NCH = KSL / BK;        // 64 chunks per block
constexpr int LDA = 40;              // LDS row stride in halves (80 B, 16B-aligned, 2-way banks)

typedef _Float16 f16x8 __attribute__((ext_vector_type(8)));
typedef __fp16  fp16x2 __attribute__((ext_vector_type(2)));
typedef float f32x4 __attribute__((ext_vector_type(4)));

__device__ __forceinline__ unsigned int cvt2(float a, float b) {
    fp16x2 p = __builtin_amdgcn_cvt_pkrtz(a, b);   // v_cvt_pkrtz_f16_f32
    return __builtin_bit_cast(unsigned int, p);
}

// ===================== fused GEMM (+pooling) =====================
// C[672x848] += x[672x32768] * concat(W_base, lora_A)[848x32768]^T   (fp16 MFMA, fp32 acc)
// pooled[b][d] += sum over this block's A elements (only nt==0 blocks -> each elem once)
__global__ __launch_bounds__(256, 2)
void gemm_pool_kernel(const float* __restrict__ x, const float* __restrict__ Wb,
                      const float* __restrict__ lA, float* __restrict__ C,
                      float* __restrict__ pooled)
{
    __shared__ _Float16 As[BM * LDA];
    __shared__ _Float16 Bs[BN * LDA];

    const int nt = blockIdx.x;   // 0..6
    const int mt = blockIdx.y;   // 0..5
    const int s  = blockIdx.z;   // 0..15
    const int t  = threadIdx.x;  // 0..255
    const int r  = t >> 1;       // staged row 0..127
    const int h  = t & 1;        // which 16-float half of the 32-wide chunk
    const int kbase = s * KSL + h * 16;

    int gm = mt * BM + r;
    const bool mval = (gm < Mz);
    if (!mval) gm = Mz - 1;                      // clamp: duplicate work, discarded
    const float* pa = x + (size_t)gm * Kz + kbase;

    int gn = nt * BN + r;
    if (gn >= Nz) gn = Nz - 1;                   // clamp: garbage cols, discarded
    const float* pb = (gn < OUTz) ? (Wb + (size_t)gn * Kz + kbase)
                                  : (lA + (size_t)(gn - OUTz) * Kz + kbase);

    const int wave = t >> 6, lane = t & 63;
    const int wr = (wave >> 1) * 64;             // wave's 64x64 quadrant
    const int wc = (wave & 1) * 64;
    const int fl = lane & 15;
    const int ko = (lane >> 4) * 8;              // k offset of this lane's frag

    f32x4 acc[4][4] = {};

    float4 ca[4], cb[4];
    #pragma unroll
    for (int q = 0; q < 4; ++q) {
        ca[q] = *(const float4*)(pa + 4 * q);
        cb[q] = *(const float4*)(pb + 4 * q);
    }

    _Float16* wA = As + r * LDA + h * 16;
    _Float16* wB = Bs + r * LDA + h * 16;

    const bool do_pool = (nt == 0) && mval;
    float* poolrow = pooled + (gm / Vz) * Dz;

    for (int c = 0; c < NCH; ++c) {
        if (do_pool) {  // 16 consecutive k all share one d ( = k>>6 )
            float ssum = (ca[0].x + ca[0].y + ca[0].z + ca[0].w)
                       + (ca[1].x + ca[1].y + ca[1].z + ca[1].w)
                       + (ca[2].x + ca[2].y + ca[2].z + ca[2].w)
                       + (ca[3].x + ca[3].y + ca[3].z + ca[3].w);
            atomicAdd(poolrow + ((kbase + c * BK) >> 6), ssum);
        }
        *((uint4*)wA)     = make_uint4(cvt2(ca[0].x, ca[0].y), cvt2(ca[0].z, ca[0].w),
                                       cvt2(ca[1].x, ca[1].y), cvt2(ca[1].z, ca[1].w));
        *((uint4*)wA + 1) = make_uint4(cvt2(ca[2].x, ca[2].y), cvt2(ca[2].z, ca[2].w),
                                       cvt2(ca[3].x, ca[3].y), cvt2(ca[3].z, ca[3].w));
        *((uint4*)wB)     = make_uint4(cvt2(cb[0].x, cb[0].y), cvt2(cb[0].z, cb[0].w),
                                       cvt2(cb[1].x, cb[1].y), cvt2(cb[1].z, cb[1].w));
        *((uint4*)wB + 1) = make_uint4(cvt2(cb[2].x, cb[2].y), cvt2(cb[2].z, cb[2].w),
                                       cvt2(cb[3].x, cb[3].y), cvt2(cb[3].z, cb[3].w));
        __syncthreads();

        if (c + 1 < NCH) {   // prefetch next chunk; vmcnt waited only at next cvt (after MFMA)
            const float* qa = pa + (c + 1) * BK;
            const float* qb = pb + (c + 1) * BK;
            #pragma unroll
            for (int q = 0; q < 4; ++q) {
                ca[q] = *(const float4*)(qa + 4 * q);
                cb[q] = *(const float4*)(qb + 4 * q);
            }
        }

        f16x8 af[4], bfr[4];
        #pragma unroll
        for (int i = 0; i < 4; ++i)
            af[i] = *(const f16x8*)(As + (wr + i * 16 + fl) * LDA + ko);
        #pragma unroll
        for (int j = 0; j < 4; ++j)
            bfr[j] = *(const f16x8*)(Bs + (wc + j * 16 + fl) * LDA + ko);
        #pragma unroll
        for (int i = 0; i < 4; ++i)
            #pragma unroll
            for (int j = 0; j < 4; ++j)
                acc[i][j] = __builtin_amdgcn_mfma_f32_16x16x32_f16(af[i], bfr[j], acc[i][j], 0, 0, 0);
        __syncthreads();
    }

    // epilogue: split-K accumulate via fp32 atomics.  C/D layout: col=lane&15, row=quad*4+reg
    const int rq = (lane >> 4) * 4;
    #pragma unroll
    for (int i = 0; i < 4; ++i) {
        const int gmr0 = mt * BM + wr + i * 16 + rq;
        #pragma unroll
        for (int j = 0; j < 4; ++j) {
            const int gnc = nt * BN + wc + j * 16 + fl;
            if (gnc < Nz) {
                #pragma unroll
                for (int q = 0; q < 4; ++q) {
                    const int gmr = gmr0 + q;
                    if (gmr < Mz) atomicAdd(&C[(size_t)gmr * Nz + gnc], acc[i][j][q]);
                }
            }
        }
    }
}

// ===================== router =====================
__global__ __launch_bounds__(256)
void router_kernel(const float* __restrict__ pooled_raw,
                   const float* __restrict__ Wr1, const float* __restrict__ br1,
                   const float* __restrict__ Wr2, const float* __restrict__ br2,
                   float* __restrict__ probs_out, int* __restrict__ tki, float* __restrict__ tkw)
{
    const int b = blockIdx.x, t = threadIdx.x;
    __shared__ float pl[Dz];
    __shared__ float hbuf[Hz];
    __shared__ float lg[Ez];

    for (int d = t; d < Dz; d += 256)
        pl[d] = pooled_raw[b * Dz + d] * (1.0f / (float)(Vz * Pz));
    __syncthreads();

    {   // h = gelu(pooled @ Wr1^T + br1), exact erf gelu
        const float* w = Wr1 + (size_t)t * Dz;
        float a = br1[t];
        for (int d = 0; d < Dz; ++d) a = fmaf(pl[d], w[d], a);
        hbuf[t] = 0.5f * a * (1.0f + erff(a * 0.70710678118654752440f));
    }
    __syncthreads();

    if (t < Ez) {
        const float* w = Wr2 + (size_t)t * Hz;
        float a = br2[t];
        for (int j = 0; j < Hz; ++j) a = fmaf(hbuf[j], w[j], a);
        lg[t] = a;
    }
    __syncthreads();

    if (t == 0) {
        float mx = lg[0];
        for (int e = 1; e < Ez; ++e) mx = fmaxf(mx, lg[e]);
        float p[Ez], ssum = 0.0f;
        for (int e = 0; e < Ez; ++e) { p[e] = expf(lg[e] - mx); ssum += p[e]; }
        const float inv = 1.0f / ssum;
        for (int e = 0; e < Ez; ++e) { p[e] *= inv; probs_out[b * Ez + e] = p[e]; }
        int i0 = 0;
        for (int e = 1; e < Ez; ++e) if (p[e] > p[i0]) i0 = e;     // strict > : lowest index wins ties
        int i1 = (i0 == 0) ? 1 : 0;
        for (int e = 0; e < Ez; ++e) if (e != i0 && p[e] > p[i1]) i1 = e;
        float s2 = p[i0] + p[i1];
        if (s2 < 1e-6f) s2 = 1e-6f;                                 // jnp.clip(sum, 1e-6)
        tki[b * 2] = i0; tki[b * 2 + 1] = i1;
        tkw[b * 2] = p[i0] / s2; tkw[b * 2 + 1] = p[i1] / s2;
    }
}

// ===================== combine =====================
// out[m,o] = C[m,o] + b_base[o] + w0*dot16(low[e0,m,:], lora_B[e0,o,:]) + w1*dot16(...)
__global__ __launch_bounds__(256)
void combine_kernel(const float* __restrict__ C, const float* __restrict__ bb,
                    const float* __restrict__ loraB,
                    const int* __restrict__ tki, const float* __restrict__ tkw,
                    float* __restrict__ out)
{
    const int m = blockIdx.x;        // 0..671
    const int t = threadIdx.x;
    const int b = m / Vz;
    const int e0 = tki[b * 2], e1 = tki[b * 2 + 1];
    const float w0 = tkw[b * 2], w1 = tkw[b * 2 + 1];

    __shared__ float lw[2 * Rz];
    if (t < 2 * Rz) {
        const int e = (t < Rz) ? e0 : e1;
        lw[t] = C[(size_t)m * Nz + OUTz + e * Rz + (t & (Rz - 1))];
    }
    __syncthreads();

    for (int o = t; o < OUTz; o += 256) {
        float acc = C[(size_t)m * Nz + o] + bb[o];
        const float* B0 = loraB + ((size_t)e0 * OUTz + o) * Rz;
        const float* B1 = loraB + ((size_t)e1 * OUTz + o) * Rz;
        float d0 = 0.0f, d1 = 0.0f;
        #pragma unroll
        for (int rr = 0; rr < Rz; ++rr) {
            d0 = fmaf(lw[rr], B0[rr], d0);
            d1 = fmaf(lw[Rz + rr], B1[rr], d1);
        }
        out[(size_t)m * OUTz + o] = acc + w0 * d0 + w1 * d1;   // SCALING == 1.0
    }
}

// ===================== launch =====================
extern "C" void kernel_launch(void* const* d_in, const int* in_sizes, int n_in,
                              void* d_out, int out_size, void* d_ws, size_t ws_size,
                              hipStream_t stream)
{
    const float* x   = (const float*)d_in[0];
    const float* Wb  = (const float*)d_in[1];
    const float* bb  = (const float*)d_in[2];
    const float* Wr1 = (const float*)d_in[3];
    const float* br1 = (const float*)d_in[4];
    const float* Wr2 = (const float*)d_in[5];
    const float* br2 = (const float*)d_in[6];
    const float* lA  = (const float*)d_in[7];
    const float* lB  = (const float*)d_in[8];
    float* out = (float*)d_out;

    float* C      = (float*)d_ws;            // 672*848 fp32
    float* pooled = C + (size_t)Mz * Nz;     // 32*512 fp32
    int*   tki    = (int*)(pooled + Bz * Dz);
    float* tkw    = (float*)(tki + 2 * Bz);

    // zero split-K accumulator + pooled (ws is poisoned before every launch)
    (void)hipMemsetAsync(d_ws, 0, ((size_t)Mz * Nz + Bz * Dz) * sizeof(float), stream);

    gemm_pool_kernel<<<dim3(7, 6, SPLIT), 256, 0, stream>>>(x, Wb, lA, C, pooled);
    router_kernel<<<Bz, 256, 0, stream>>>(pooled, Wr1, br1, Wr2, br2,
                                          out + (size_t)Mz * OUTz, tki, tkw);
    combine_kernel<<<Mz, 256, 0, stream>>>(C, bb, lB, tki, tkw, out);
}